// Round 5
// baseline (111.062 us; speedup 1.0000x reference)
//
#include <hip/hip_runtime.h>
#include <hip/hip_bf16.h>
#include <math.h>

#define BATCH   2048
#define NINTRS  256
#define VALID   128
#define NATOMS  256
#define DDIM    28   // 3*9+1
#define NCOLS   224  // DDIM*8
#define PCOLS   256  // padded cols per kg (16B-DMA-friendly)

typedef float  f32x4  __attribute__((ext_vector_type(4)));
typedef short  bf16x8 __attribute__((ext_vector_type(8)));

__device__ __forceinline__ unsigned short f32_to_bf16(float f) {
    unsigned int u = __float_as_uint(f);
    u = (u + 0x7FFFu + ((u >> 16) & 1u)) >> 16;   // RNE
    return (unsigned short)u;
}

// ---------------------------------------------------------------------------
// Pre-pass: BsT[kg][col][j] bf16, kg = a/8 (0..31), col = d*8+c (0..223,
// padded to 256), j = a%8. 16B chunk == MFMA B-fragment unit. 128 KB,
// L2-resident, consumed by every block via coalesced 16B DMA.
// ---------------------------------------------------------------------------
__global__ __launch_bounds__(256)
void build_bst(const float* __restrict__ atoms, unsigned short* __restrict__ bst)
{
    const int t   = blockIdx.x * 256 + threadIdx.x;   // 0..8191
    const int col = t & (PCOLS - 1);
    const int kg  = t >> 8;             // 0..31
    bf16x8 v;
    if (col < NCOLS) {
        const int a0 = kg * 8;
        #pragma unroll
        for (int j = 0; j < 8; ++j)
            v[j] = (short)f32_to_bf16(atoms[(size_t)(a0 + j) * NCOLS + col]);
    } else {
        #pragma unroll
        for (int j = 0; j < 8; ++j) v[j] = 0;
    }
    *(bf16x8*)(bst + (size_t)t * 8) = v;
}

// ---------------------------------------------------------------------------
// Main: one block per ray. GEMM D[pt, d*8+c] = sum_a q[pt,a]*atoms[a,d,c]
// via MFMA; q (f32, swizzled) and BsT (bf16) staged global->LDS with 16B
// global_load_lds, double-buffered, counted vmcnt (8 DMA/step/wave).
// TWO barriers per K-step: (1) after vmcnt — stage(ks) landed for all
// waves; (2) after MFMAs — all waves done READING buffer ks&1, so the
// refill (which overwrites block-shared bbuf) is WAR-safe.
// ---------------------------------------------------------------------------
__global__ __launch_bounds__(256, 2)
void shdict_fused(const float* __restrict__ q,      // [BATCH*VALID][256]
                  const unsigned short* __restrict__ bst, // [32][256][8] bf16
                  const float* __restrict__ ipts,   // [BATCH*VALID][3]
                  const float* __restrict__ intr,   // [BATCH][257]
                  const float* __restrict__ raysd,  // [BATCH][3]
                  float* __restrict__ out_rgb,      // [BATCH][3]
                  float* __restrict__ out_alpha,    // [BATCH][256]
                  float* __restrict__ out_depth)    // [BATCH]
{
    __shared__ float qbuf[2 * 4 * 1024];   // 32 KB: [buf][wave][32 rows x 32 f32]
    __shared__ char  bbuf[2 * 16384];      // 32 KB: [buf][kg-quarter 4][col 256][16B]
    __shared__ float w_lds[VALID][9];      // trilinear weights (+1 pad)
    __shared__ float pr_lds[VALID][5];     // rgb0,rgb1,rgb2,sigma (+1 pad)
    float* interp = qbuf;                  // [128][29] f32, aliases qbuf (dead after K-loop)

    const int ray  = blockIdx.x;
    const int tid  = threadIdx.x;
    const int lane = tid & 63;
    const int wav  = tid >> 6;

    // ---- scalar input loads FIRST; drain so vmcnt counting stays exact ----
    const float rdx = raysd[ray*3+0], rdy = raysd[ray*3+1], rdz = raysd[ray*3+2];
    float px = 0.f, py = 0.f, pz = 0.f;
    if (tid < VALID) {
        const int n = ray * VALID + tid;
        px = ipts[n*3+0]*128.0f + 1e-5f;
        py = ipts[n*3+1]*128.0f + 1e-5f;
        pz = ipts[n*3+2]*128.0f + 1e-5f;
    }
    asm volatile("s_waitcnt vmcnt(0)" ::: "memory");

    // ---- DMA staging setup ----
    // q: wave-private 4 KB slice per buffer; LDS linear, global pre-swizzled
    // (rule #21): lane l writes (row = j*8 + l/8, chunk l&7); carries global
    // chunk (l&7)^(row&7).
    const int srow   = lane >> 3;
    const int schunk = (lane & 7) ^ srow;
    const char* gq = (const char*)q
        + ((size_t)(ray * VALID + wav * 32 + srow) << 10)
        + ((size_t)schunk << 4);
    char* lq = (char*)qbuf + (wav << 12);

    // B: wave w stages kg-quarter w (4096 B = 4 x 16B-instr) per buffer.
    const char* gb = (const char*)bst + (size_t)wav * 4096;
    char* lb = (char*)bbuf + wav * 4096;

    auto stage_q = [&](int ks, int bufi) {
        #pragma unroll
        for (int j = 0; j < 4; ++j) {
            __builtin_amdgcn_global_load_lds(
                (const __attribute__((address_space(1))) void*)(gq + ks * 128 + j * 8192),
                (__attribute__((address_space(3))) void*)(lq + bufi * 16384 + j * 1024),
                16, 0, 0);
        }
    };
    auto stage_b = [&](int ks, int bufi) {
        const char* s = gb + (size_t)ks * 16384 + (size_t)lane * 16;
        char*       d = lb + bufi * 16384;
        #pragma unroll
        for (int j = 0; j < 4; ++j) {
            __builtin_amdgcn_global_load_lds(
                (const __attribute__((address_space(1))) void*)(s + j * 1024),
                (__attribute__((address_space(3))) void*)(d + j * 1024),
                16, 0, 0);
        }
    };

    // Prologue: 2 K-steps in flight (8 DMA instrs each: 4 q + 4 B)
    stage_q(0, 0); stage_b(0, 0);
    stage_q(1, 1); stage_b(1, 1);

    // ---- VALU-only while DMA flies: SH basis + trilinear weights ----
    const float ss = rdx*rdx + rdy*rdy + rdz*rdz;
    const float rn = rsqrtf(ss);
    const float x = rdx*rn, y = rdy*rn, z = rdz*rn;
    float sh[9];
    sh[0] = 0.28209479177387814f;
    sh[1] = -0.4886025119029199f * y;
    sh[2] =  0.4886025119029199f * z;
    sh[3] = -0.4886025119029199f * x;
    sh[4] =  1.0925484305920792f * x * y;
    sh[5] = -1.0925484305920792f * y * z;
    sh[6] =  0.31539156525252005f * (2.0f*z*z - x*x - y*y);
    sh[7] = -1.0925484305920792f * x * z;
    sh[8] =  0.5462742152960396f * (x*x - y*y);

    if (tid < VALID) {
        const float fx = px - floorf(px);
        const float fy = py - floorf(py);
        const float fz = pz - floorf(pz);
        #pragma unroll
        for (int c = 0; c < 8; ++c) {
            const float wx = (c & 4) ? fx : 1.0f - fx;
            const float wy = (c & 2) ? fy : 1.0f - fy;
            const float wz = (c & 1) ? fz : 1.0f - fz;
            w_lds[tid][c] = wx * wy * wz;
        }
    }

    // ---- K-loop: 8 steps of K=32; 28 MFMAs/step/wave ----
    f32x4 acc[2][14];
    #pragma unroll
    for (int m = 0; m < 2; ++m)
        #pragma unroll
        for (int nt = 0; nt < 14; ++nt)
            acc[m][nt] = (f32x4){0.f, 0.f, 0.f, 0.f};

    const int row  = lane & 15;
    const int kgrp = lane >> 4;
    const int key  = row & 7;

    #pragma unroll
    for (int ks = 0; ks < 8; ++ks) {
        // stage(ks) complete when only stage(ks+1)'s 8 instrs remain
        if (ks < 7) asm volatile("s_waitcnt vmcnt(8)" ::: "memory");
        else        asm volatile("s_waitcnt vmcnt(0)" ::: "memory");
        __builtin_amdgcn_s_barrier();      // barrier 1: stage(ks) visible to all
        asm volatile("" ::: "memory");

        // A fragments (q rows, swizzled f32 -> bf16)
        const char* rb = (char*)qbuf + (ks & 1) * 16384 + (wav << 12);
        f32x4 a0l = *(const f32x4*)(rb + row*128      + (((2*kgrp+0) ^ key) << 4));
        f32x4 a0h = *(const f32x4*)(rb + row*128      + (((2*kgrp+1) ^ key) << 4));
        f32x4 a1l = *(const f32x4*)(rb + (row+16)*128 + (((2*kgrp+0) ^ key) << 4));
        f32x4 a1h = *(const f32x4*)(rb + (row+16)*128 + (((2*kgrp+1) ^ key) << 4));
        bf16x8 af0, af1;
        #pragma unroll
        for (int j = 0; j < 4; ++j) {
            af0[j]   = (short)f32_to_bf16(a0l[j]);
            af0[j+4] = (short)f32_to_bf16(a0h[j]);
            af1[j]   = (short)f32_to_bf16(a1l[j]);
            af1[j+4] = (short)f32_to_bf16(a1h[j]);
        }

        // B fragments + MFMA, 14 N-tiles
        const char* bb = (char*)bbuf + (ks & 1) * 16384 + kgrp * 4096;
        #pragma unroll
        for (int nt = 0; nt < 14; ++nt) {
            bf16x8 bf = *(const bf16x8*)(bb + ((nt*16 + row) << 4));
            acc[0][nt] = __builtin_amdgcn_mfma_f32_16x16x32_bf16(af0, bf, acc[0][nt], 0, 0, 0);
            acc[1][nt] = __builtin_amdgcn_mfma_f32_16x16x32_bf16(af1, bf, acc[1][nt], 0, 0, 0);
        }

        // barrier 2: ALL waves done reading buffer ks&1 (MFMAs consumed the
        // ds_reads), so overwriting block-shared bbuf[ks&1] is WAR-safe.
        asm volatile("" ::: "memory");
        __builtin_amdgcn_s_barrier();
        asm volatile("" ::: "memory");
        if (ks + 2 < 8) { stage_q(ks + 2, ks & 1); stage_b(ks + 2, ks & 1); }
    }
    __syncthreads();   // everyone done; interp may alias qbuf

    // ---- Epilogue: interp[pt][d] = sum_c D[pt, d*8+c] * w[pt][c] ----
    // D layout: lane holds D[row=(l>>4)*4+r][col=l&15]; col = kph*8 + cc.
    const int cc  = lane & 7;
    const int kph = (lane & 15) >> 3;
    #pragma unroll
    for (int m = 0; m < 2; ++m) {
        const int ptb = wav*32 + m*16 + kgrp*4;
        #pragma unroll
        for (int nt = 0; nt < 14; ++nt) {
            const int d = nt*2 + kph;
            #pragma unroll
            for (int r = 0; r < 4; ++r) {
                float t = acc[m][nt][r] * w_lds[ptb + r][cc];
                t += __shfl_xor(t, 1);
                t += __shfl_xor(t, 2);
                t += __shfl_xor(t, 4);
                if (cc == 0) interp[(ptb + r) * 29 + d] = t;
            }
        }
    }
    __syncthreads();

    // ---- SH contraction per point ----
    if (tid < VALID) {
        const float* ip = interp + tid * 29;
        float r0 = 0.f, r1 = 0.f, r2 = 0.f;
        #pragma unroll
        for (int j = 0; j < 9; ++j) {
            r0 = fmaf(sh[j], ip[j],      r0);
            r1 = fmaf(sh[j], ip[9 + j],  r1);
            r2 = fmaf(sh[j], ip[18 + j], r2);
        }
        pr_lds[tid][0] = r0;
        pr_lds[tid][1] = r1;
        pr_lds[tid][2] = r2;
        pr_lds[tid][3] = ip[27];
    }
    __syncthreads();

    // ---- Render scan (wave 0): 2 samples per lane ----
    if (wav == 0) {
        const float rnorm = sqrtf(ss);
        const int i0 = lane * 2;
        const float t0 = intr[ray*257 + i0];
        const float t1 = intr[ray*257 + i0 + 1];
        const float t2 = intr[ray*257 + i0 + 2];
        const float d0 = (t1 - t0) * rnorm;
        const float d1 = (t2 - t1) * rnorm;
        const float s0 = fmaxf(pr_lds[i0][3],     0.0f);
        const float s1 = fmaxf(pr_lds[i0 + 1][3], 0.0f);
        const float a0 = 1.0f - __expf(-s0 * d0);
        const float a1 = 1.0f - __expf(-s1 * d1);
        const float f0 = 1.0f - a0 + 1e-10f;
        const float f1 = 1.0f - a1 + 1e-10f;

        float pprod = f0 * f1;
        #pragma unroll
        for (int off = 1; off < 64; off <<= 1) {
            float v = __shfl_up(pprod, off);
            if (lane >= off) pprod *= v;
        }
        float excl = __shfl_up(pprod, 1);
        if (lane == 0) excl = 1.0f;

        const float tr0 = excl;
        const float tr1 = excl * f0;
        const float al0 = a0 * tr0;
        const float al1 = a1 * tr1;
        const float mid0 = 0.5f * (t0 + t1);
        const float mid1 = 0.5f * (t1 + t2);

        const float r0 = 1.0f / (1.0f + __expf(-pr_lds[i0][0]));
        const float g0 = 1.0f / (1.0f + __expf(-pr_lds[i0][1]));
        const float b0 = 1.0f / (1.0f + __expf(-pr_lds[i0][2]));
        const float r1 = 1.0f / (1.0f + __expf(-pr_lds[i0 + 1][0]));
        const float g1 = 1.0f / (1.0f + __expf(-pr_lds[i0 + 1][1]));
        const float b1 = 1.0f / (1.0f + __expf(-pr_lds[i0 + 1][2]));

        float sum_r = al0*r0 + al1*r1;
        float sum_g = al0*g0 + al1*g1;
        float sum_b = al0*b0 + al1*b1;
        float sum_d = al0*mid0 + al1*mid1;
        float sum_a = al0 + al1;
        #pragma unroll
        for (int off = 1; off < 64; off <<= 1) {
            sum_r += __shfl_xor(sum_r, off);
            sum_g += __shfl_xor(sum_g, off);
            sum_b += __shfl_xor(sum_b, off);
            sum_d += __shfl_xor(sum_d, off);
            sum_a += __shfl_xor(sum_a, off);
        }
        if (lane == 0) {
            const float bkgd = 1.0f - sum_a;
            out_rgb[ray*3 + 0] = sum_r + bkgd;
            out_rgb[ray*3 + 1] = sum_g + bkgd;
            out_rgb[ray*3 + 2] = sum_b + bkgd;
            out_depth[ray]     = sum_d;
        }
        float2 av; av.x = a0; av.y = a1;
        *(float2*)(out_alpha + (size_t)ray*NINTRS + i0) = av;
        float2 zz; zz.x = 0.0f; zz.y = 0.0f;
        *(float2*)(out_alpha + (size_t)ray*NINTRS + VALID + i0) = zz;
    }
}

extern "C" void kernel_launch(void* const* d_in, const int* in_sizes, int n_in,
                              void* d_out, int out_size, void* d_ws, size_t ws_size,
                              hipStream_t stream)
{
    const float* q     = (const float*)d_in[0];
    const float* atoms = (const float*)d_in[1];
    const float* ipts  = (const float*)d_in[2];
    const float* intr  = (const float*)d_in[3];
    const float* raysd = (const float*)d_in[4];
    // d_in[5] (flat_idx) is b*NINTRS+i by construction; derived analytically.

    float* out = (float*)d_out;
    float* out_rgb   = out;
    float* out_alpha = out + BATCH*3;
    float* out_depth = out + BATCH*3 + (size_t)BATCH*NINTRS;

    unsigned short* bst = (unsigned short*)d_ws;   // 131072 B needed

    build_bst<<<32, 256, 0, stream>>>(atoms, bst);
    shdict_fused<<<BATCH, 256, 0, stream>>>(q, bst, ipts, intr, raysd,
                                            out_rgb, out_alpha, out_depth);
}

// Round 6
// 62.749 us; speedup vs baseline: 1.7699x; 1.7699x over previous
//
#include <hip/hip_runtime.h>
#include <hip/hip_bf16.h>
#include <math.h>

#define BATCH   2048
#define NINTRS  256
#define VALID   128
#define NATOMS  256
#define DDIM    28   // 3*9+1

typedef float  f32x4  __attribute__((ext_vector_type(4)));
typedef short  bf16x8 __attribute__((ext_vector_type(8)));

__device__ __forceinline__ unsigned short f32_to_bf16(float f) {
    unsigned int u = __float_as_uint(f);
    u = (u + 0x7FFFu + ((u >> 16) & 1u)) >> 16;   // RNE
    return (unsigned short)u;
}

// ---------------------------------------------------------------------------
// Pre-pass: ab[d][a] = 16B chunk {bf16 atoms[a][d][c], c=0..7}. [28][256] chunks
// = 112 KB, L2-resident. Main kernel's phase B reads it with lane-stride-16B
// fully-coalesced loads (1 KB/wave/instr).
// ---------------------------------------------------------------------------
__global__ __launch_bounds__(256)
void build_atomsB(const float* __restrict__ atoms, unsigned short* __restrict__ ab)
{
    const int t = blockIdx.x * 256 + threadIdx.x;   // 0..7167
    const int d = t >> 8;          // 0..27
    const int a = t & 255;
    const float* src = atoms + ((size_t)a * DDIM + d) * 8;
    f32x4 v0 = *(const f32x4*)(src);
    f32x4 v1 = *(const f32x4*)(src + 4);
    bf16x8 o;
    #pragma unroll
    for (int j = 0; j < 4; ++j) {
        o[j]   = (short)f32_to_bf16(v0[j]);
        o[j+4] = (short)f32_to_bf16(v1[j]);
    }
    *(bf16x8*)(ab + (size_t)t * 8) = o;
}

// ---------------------------------------------------------------------------
// Main: one block per ray.
//   phase B: SH-contract ab -> Bs[32 col][256 a] bf16 in LDS (coalesced reads,
//            issued BEFORE the DMA prologue so their in-order vmcnt retire
//            doesn't drain the staging pipeline).
//   K-loop:  C[pt,col] = sum_a q[pt,a]*Bs[col,a] via MFMA; q staged
//            global->LDS DMA, wave-private slices, TRIPLE-buffered,
//            counted vmcnt, no barriers.
//   epilogue: trilinear-weight c-reduction + transmittance scan (wave 0).
// ---------------------------------------------------------------------------
__global__ __launch_bounds__(256, 2)
void shdict_fused(const float* __restrict__ q,      // [BATCH*VALID][256]
                  const unsigned short* __restrict__ ab,  // [28][256] bf16x8
                  const float* __restrict__ ipts,   // [BATCH*VALID][3]
                  const float* __restrict__ intr,   // [BATCH][257]
                  const float* __restrict__ raysd,  // [BATCH][3]
                  float* __restrict__ out_rgb,      // [BATCH][3]
                  float* __restrict__ out_alpha,    // [BATCH][256]
                  float* __restrict__ out_depth)    // [BATCH]
{
    __shared__ char  bs[32 * 256 * 2];      // 16 KB Bs[col][a] bf16, XOR-swizzled
    __shared__ float qbuf[3 * 4 * 1024];    // 48 KB: [buf][wave][32 rows x 32 f32]
    __shared__ float w_lds[VALID][9];       // trilinear weights (+1 pad)
    __shared__ float pr_lds[VALID][5];      // rgb0,rgb1,rgb2,sigma (+1 pad)

    const int ray  = blockIdx.x;
    const int tid  = threadIdx.x;
    const int lane = tid & 63;
    const int wav  = tid >> 6;

    // ---- scalar input loads FIRST; drain so later vmcnt counting is exact ----
    const float rdx = raysd[ray*3+0], rdy = raysd[ray*3+1], rdz = raysd[ray*3+2];
    float px = 0.f, py = 0.f, pz = 0.f;
    if (tid < VALID) {
        const int n = ray * VALID + tid;
        px = ipts[n*3+0]*128.0f + 1e-5f;
        py = ipts[n*3+1]*128.0f + 1e-5f;
        pz = ipts[n*3+2]*128.0f + 1e-5f;
    }
    asm volatile("s_waitcnt vmcnt(0)" ::: "memory");

    // ---- phase-B loads: 28 coalesced 16B chunks for a = tid. Issued before
    // the DMA prologue: in-order vmcnt retire means consuming them waits only
    // on themselves, leaving the 12 staging DMAs in flight. ----
    bf16x8 abv[28];
    #pragma unroll
    for (int d = 0; d < 28; ++d)
        abv[d] = *(const bf16x8*)(ab + ((size_t)(d * 256 + tid)) * 8);

    // ---- DMA staging setup (q only) ----
    // Wave-private 4 KB slice per buffer; LDS linear, global pre-swizzled
    // (rule #21): lane l writes (row = j*8 + l/8, chunk l&7); carries global
    // chunk (l&7)^(row&7).
    const int srow   = lane >> 3;
    const int schunk = (lane & 7) ^ srow;
    const char* gq = (const char*)q
        + ((size_t)(ray * VALID + wav * 32 + srow) << 10)
        + ((size_t)schunk << 4);
    char* lq = (char*)qbuf + (wav << 12);

    auto stage_q = [&](int ks, int bufi) {
        #pragma unroll
        for (int j = 0; j < 4; ++j) {
            __builtin_amdgcn_global_load_lds(
                (const __attribute__((address_space(1))) void*)(gq + ks * 128 + j * 8192),
                (__attribute__((address_space(3))) void*)(lq + bufi * 16384 + j * 1024),
                16, 0, 0);
        }
    };

    // Prologue: 3 K-steps in flight (12 DMA instrs)
    stage_q(0, 0);
    stage_q(1, 1);
    stage_q(2, 2);

    // ---- SH basis (VALU, overlaps DMA) ----
    const float ss = rdx*rdx + rdy*rdy + rdz*rdz;
    const float rn = rsqrtf(ss);
    const float x = rdx*rn, y = rdy*rn, z = rdz*rn;
    float sh[9];
    sh[0] = 0.28209479177387814f;
    sh[1] = -0.4886025119029199f * y;
    sh[2] =  0.4886025119029199f * z;
    sh[3] = -0.4886025119029199f * x;
    sh[4] =  1.0925484305920792f * x * y;
    sh[5] = -1.0925484305920792f * y * z;
    sh[6] =  0.31539156525252005f * (2.0f*z*z - x*x - y*y);
    sh[7] = -1.0925484305920792f * x * z;
    sh[8] =  0.5462742152960396f * (x*x - y*y);

    // ---- phase B: contract abv -> Bs[col = kp*8+c][a = tid] ----
    {
        const int a = tid;
        float accB[3][8];
        #pragma unroll
        for (int k = 0; k < 3; ++k)
            #pragma unroll
            for (int c = 0; c < 8; ++c) accB[k][c] = 0.0f;
        #pragma unroll
        for (int d = 0; d < 27; ++d) {
            const int kp = d / 9, j = d - kp * 9;
            const float s = sh[j];
            const unsigned int* u = (const unsigned int*)&abv[d];
            #pragma unroll
            for (int i = 0; i < 4; ++i) {
                const float flo = __uint_as_float(u[i] << 16);
                const float fhi = __uint_as_float(u[i] & 0xffff0000u);
                accB[kp][2*i]   = fmaf(s, flo, accB[kp][2*i]);
                accB[kp][2*i+1] = fmaf(s, fhi, accB[kp][2*i+1]);
            }
        }
        #pragma unroll
        for (int kp = 0; kp < 3; ++kp)
            #pragma unroll
            for (int c = 0; c < 8; ++c) {
                const int col = kp*8 + c;
                unsigned byte = ((unsigned)col << 9) + ((unsigned)a << 1);
                byte ^= (unsigned)((col & 7) << 4);
                *(unsigned short*)(bs + byte) = f32_to_bf16(accB[kp][c]);
            }
        // sigma row (d=27): already bf16 — store raw
        const unsigned short* sv = (const unsigned short*)&abv[27];
        #pragma unroll
        for (int c = 0; c < 8; ++c) {
            const int col = 24 + c;
            unsigned byte = ((unsigned)col << 9) + ((unsigned)a << 1);
            byte ^= (unsigned)((col & 7) << 4);
            *(unsigned short*)(bs + byte) = sv[c];
        }
    }

    // ---- phase A: trilinear weights ----
    if (tid < VALID) {
        const float fx = px - floorf(px);
        const float fy = py - floorf(py);
        const float fz = pz - floorf(pz);
        #pragma unroll
        for (int c = 0; c < 8; ++c) {
            const float wx = (c & 4) ? fx : 1.0f - fx;
            const float wy = (c & 2) ? fy : 1.0f - fy;
            const float wz = (c & 1) ? fz : 1.0f - fz;
            w_lds[tid][c] = wx * wy * wz;
        }
    }
    __syncthreads();   // bs + w_lds ready (barrier does NOT break vmcnt counting)

    // ---- K-loop: 8 steps of K=32, triple-buffered, barrier-free ----
    f32x4 acc[2][2];
    #pragma unroll
    for (int m = 0; m < 2; ++m)
        #pragma unroll
        for (int n = 0; n < 2; ++n)
            acc[m][n] = (f32x4){0.f, 0.f, 0.f, 0.f};

    const int row  = lane & 15;
    const int kgrp = lane >> 4;
    const int key  = row & 7;

    #pragma unroll
    for (int ks = 0; ks < 8; ++ks) {
        // outstanding: stages ks..min(ks+2,7); wait for stage ks to land
        if (ks < 6)      asm volatile("s_waitcnt vmcnt(8)" ::: "memory");
        else if (ks == 6) asm volatile("s_waitcnt vmcnt(4)" ::: "memory");
        else              asm volatile("s_waitcnt vmcnt(0)" ::: "memory");

        const char* rb = (char*)qbuf + (ks % 3) * 16384 + (wav << 12);
        f32x4 a0l = *(const f32x4*)(rb + row*128      + (((2*kgrp+0) ^ key) << 4));
        f32x4 a0h = *(const f32x4*)(rb + row*128      + (((2*kgrp+1) ^ key) << 4));
        f32x4 a1l = *(const f32x4*)(rb + (row+16)*128 + (((2*kgrp+0) ^ key) << 4));
        f32x4 a1h = *(const f32x4*)(rb + (row+16)*128 + (((2*kgrp+1) ^ key) << 4));
        bf16x8 af0, af1;
        #pragma unroll
        for (int j = 0; j < 4; ++j) {
            af0[j]   = (short)f32_to_bf16(a0l[j]);
            af0[j+4] = (short)f32_to_bf16(a0h[j]);
            af1[j]   = (short)f32_to_bf16(a1l[j]);
            af1[j+4] = (short)f32_to_bf16(a1h[j]);
        }

        bf16x8 bfrag[2];
        const int abase = ks*32 + kgrp*8;
        #pragma unroll
        for (int nt = 0; nt < 2; ++nt) {
            const int col = nt*16 + row;
            unsigned byte = ((unsigned)col << 9) + ((unsigned)abase << 1);
            byte ^= (unsigned)((col & 7) << 4);
            bfrag[nt] = *(const bf16x8*)(bs + byte);
        }

        // ensure this wave's ds_reads of buffer ks%3 retired before the DMA
        // refill can overwrite it (DS and VMEM-to-LDS are not mutually ordered)
        asm volatile("s_waitcnt lgkmcnt(0)" ::: "memory");
        if (ks + 3 < 8) stage_q(ks + 3, ks % 3);

        acc[0][0] = __builtin_amdgcn_mfma_f32_16x16x32_bf16(af0, bfrag[0], acc[0][0], 0, 0, 0);
        acc[0][1] = __builtin_amdgcn_mfma_f32_16x16x32_bf16(af0, bfrag[1], acc[0][1], 0, 0, 0);
        acc[1][0] = __builtin_amdgcn_mfma_f32_16x16x32_bf16(af1, bfrag[0], acc[1][0], 0, 0, 0);
        acc[1][1] = __builtin_amdgcn_mfma_f32_16x16x32_bf16(af1, bfrag[1], acc[1][1], 0, 0, 0);
    }

    // ---- Epilogue: out[pt,kp] = sum_c w[pt,c] * C[pt, kp*8+c] ----
    // D layout: lane holds D[(lane>>4)*4 + r][lane&15]; col = kph*8 + cc.
    const int cc  = lane & 7;
    const int kph = (lane & 15) >> 3;
    #pragma unroll
    for (int m = 0; m < 2; ++m) {
        const int ptb = wav*32 + m*16 + kgrp*4;
        #pragma unroll
        for (int nt = 0; nt < 2; ++nt) {
            const int kp = nt*2 + kph;
            #pragma unroll
            for (int r = 0; r < 4; ++r) {
                float t = acc[m][nt][r] * w_lds[ptb + r][cc];
                t += __shfl_xor(t, 1);
                t += __shfl_xor(t, 2);
                t += __shfl_xor(t, 4);
                if (cc == 0) pr_lds[ptb + r][kp] = t;
            }
        }
    }
    __syncthreads();

    // ---- Render scan (wave 0): 2 samples per lane ----
    if (wav == 0) {
        const float rnorm = sqrtf(ss);
        const int i0 = lane * 2;
        const float t0 = intr[ray*257 + i0];
        const float t1 = intr[ray*257 + i0 + 1];
        const float t2 = intr[ray*257 + i0 + 2];
        const float d0 = (t1 - t0) * rnorm;
        const float d1 = (t2 - t1) * rnorm;
        const float s0 = fmaxf(pr_lds[i0][3],     0.0f);
        const float s1 = fmaxf(pr_lds[i0 + 1][3], 0.0f);
        const float a0 = 1.0f - __expf(-s0 * d0);
        const float a1 = 1.0f - __expf(-s1 * d1);
        const float f0 = 1.0f - a0 + 1e-10f;
        const float f1 = 1.0f - a1 + 1e-10f;

        float pprod = f0 * f1;
        #pragma unroll
        for (int off = 1; off < 64; off <<= 1) {
            float v = __shfl_up(pprod, off);
            if (lane >= off) pprod *= v;
        }
        float excl = __shfl_up(pprod, 1);
        if (lane == 0) excl = 1.0f;

        const float tr0 = excl;
        const float tr1 = excl * f0;
        const float al0 = a0 * tr0;
        const float al1 = a1 * tr1;
        const float mid0 = 0.5f * (t0 + t1);
        const float mid1 = 0.5f * (t1 + t2);

        const float r0 = 1.0f / (1.0f + __expf(-pr_lds[i0][0]));
        const float g0 = 1.0f / (1.0f + __expf(-pr_lds[i0][1]));
        const float b0 = 1.0f / (1.0f + __expf(-pr_lds[i0][2]));
        const float r1 = 1.0f / (1.0f + __expf(-pr_lds[i0 + 1][0]));
        const float g1 = 1.0f / (1.0f + __expf(-pr_lds[i0 + 1][1]));
        const float b1 = 1.0f / (1.0f + __expf(-pr_lds[i0 + 1][2]));

        float sum_r = al0*r0 + al1*r1;
        float sum_g = al0*g0 + al1*g1;
        float sum_b = al0*b0 + al1*b1;
        float sum_d = al0*mid0 + al1*mid1;
        float sum_a = al0 + al1;
        #pragma unroll
        for (int off = 1; off < 64; off <<= 1) {
            sum_r += __shfl_xor(sum_r, off);
            sum_g += __shfl_xor(sum_g, off);
            sum_b += __shfl_xor(sum_b, off);
            sum_d += __shfl_xor(sum_d, off);
            sum_a += __shfl_xor(sum_a, off);
        }
        if (lane == 0) {
            const float bkgd = 1.0f - sum_a;
            out_rgb[ray*3 + 0] = sum_r + bkgd;
            out_rgb[ray*3 + 1] = sum_g + bkgd;
            out_rgb[ray*3 + 2] = sum_b + bkgd;
            out_depth[ray]     = sum_d;
        }
        float2 av; av.x = a0; av.y = a1;
        *(float2*)(out_alpha + (size_t)ray*NINTRS + i0) = av;
        float2 zz; zz.x = 0.0f; zz.y = 0.0f;
        *(float2*)(out_alpha + (size_t)ray*NINTRS + VALID + i0) = zz;
    }
}

extern "C" void kernel_launch(void* const* d_in, const int* in_sizes, int n_in,
                              void* d_out, int out_size, void* d_ws, size_t ws_size,
                              hipStream_t stream)
{
    const float* q     = (const float*)d_in[0];
    const float* atoms = (const float*)d_in[1];
    const float* ipts  = (const float*)d_in[2];
    const float* intr  = (const float*)d_in[3];
    const float* raysd = (const float*)d_in[4];
    // d_in[5] (flat_idx) is b*NINTRS+i by construction; derived analytically.

    float* out = (float*)d_out;
    float* out_rgb   = out;
    float* out_alpha = out + BATCH*3;
    float* out_depth = out + BATCH*3 + (size_t)BATCH*NINTRS;

    unsigned short* ab = (unsigned short*)d_ws;   // 114688 B needed

    build_atomsB<<<28, 256, 0, stream>>>(atoms, ab);
    shdict_fused<<<BATCH, 256, 0, stream>>>(q, ab, ipts, intr, raysd,
                                            out_rgb, out_alpha, out_depth);
}

// Round 7
// 58.807 us; speedup vs baseline: 1.8886x; 1.0670x over previous
//
#include <hip/hip_runtime.h>
#include <hip/hip_bf16.h>
#include <math.h>

#define BATCH   2048
#define NINTRS  256
#define VALID   128
#define NATOMS  256
#define DDIM    28   // 3*9+1

typedef float  f32x4  __attribute__((ext_vector_type(4)));
typedef short  bf16x8 __attribute__((ext_vector_type(8)));

__device__ __forceinline__ unsigned short f32_to_bf16(float f) {
    unsigned int u = __float_as_uint(f);
    u = (u + 0x7FFFu + ((u >> 16) & 1u)) >> 16;   // RNE
    return (unsigned short)u;
}

// ---------------------------------------------------------------------------
// Pre-pass: ab[d][a] = 16B chunk {bf16 atoms[a][d][c], c=0..7}. [28][256] chunks
// = 112 KB, L2-resident. Main kernel's phase B reads it with lane-stride-16B
// fully-coalesced loads.
// ---------------------------------------------------------------------------
__global__ __launch_bounds__(256)
void build_atomsB(const float* __restrict__ atoms, unsigned short* __restrict__ ab)
{
    const int t = blockIdx.x * 256 + threadIdx.x;   // 0..7167
    const int d = t >> 8;          // 0..27
    const int a = t & 255;
    const float* src = atoms + ((size_t)a * DDIM + d) * 8;
    f32x4 v0 = *(const f32x4*)(src);
    f32x4 v1 = *(const f32x4*)(src + 4);
    bf16x8 o;
    #pragma unroll
    for (int j = 0; j < 4; ++j) {
        o[j]   = (short)f32_to_bf16(v0[j]);
        o[j+4] = (short)f32_to_bf16(v1[j]);
    }
    *(bf16x8*)(ab + (size_t)t * 8) = o;
}

// ---------------------------------------------------------------------------
// Main: one block per ray.
//   phase B: SH-contract ab -> Bs[32 col][256 a] bf16 in LDS (coalesced reads).
//   K-loop:  C[pt,col] = sum_a q[pt,a]*Bs[col,a] via MFMA. A-operands are
//            prefetched DIRECTLY from global q into registers with inline-asm
//            global_load_dwordx4 (cannot be sunk by the compiler), depth-3,
//            counted vmcnt + sched_barrier(0) (rule #18). No q LDS staging:
//            LDS = 23 KB -> 3+ blocks/CU (launch_bounds cap 3 waves/EU).
//   epilogue: trilinear-weight c-reduction + transmittance scan (wave 0).
// ---------------------------------------------------------------------------
__global__ __launch_bounds__(256, 3)
void shdict_fused(const float* __restrict__ q,      // [BATCH*VALID][256]
                  const unsigned short* __restrict__ ab,  // [28][256] bf16x8
                  const float* __restrict__ ipts,   // [BATCH*VALID][3]
                  const float* __restrict__ intr,   // [BATCH][257]
                  const float* __restrict__ raysd,  // [BATCH][3]
                  float* __restrict__ out_rgb,      // [BATCH][3]
                  float* __restrict__ out_alpha,    // [BATCH][256]
                  float* __restrict__ out_depth)    // [BATCH]
{
    __shared__ char  bs[32 * 256 * 2];      // 16 KB Bs[col][a] bf16, XOR-swizzled
    __shared__ float w_lds[VALID][9];       // trilinear weights (+1 pad)
    __shared__ float pr_lds[VALID][5];      // rgb0,rgb1,rgb2,sigma (+1 pad)

    const int ray  = blockIdx.x;
    const int tid  = threadIdx.x;
    const int lane = tid & 63;
    const int wav  = tid >> 6;

    // ---- scalar input loads; drained before any counted-vmcnt machinery ----
    const float rdx = raysd[ray*3+0], rdy = raysd[ray*3+1], rdz = raysd[ray*3+2];
    float px = 0.f, py = 0.f, pz = 0.f;
    if (tid < VALID) {
        const int n = ray * VALID + tid;
        px = ipts[n*3+0]*128.0f + 1e-5f;
        py = ipts[n*3+1]*128.0f + 1e-5f;
        pz = ipts[n*3+2]*128.0f + 1e-5f;
    }

    // ---- phase-B loads: 28 coalesced 16B chunks for a = tid (compiler-
    // managed; fully consumed -> vmcnt back to 0 before prefetch issues) ----
    bf16x8 abv[28];
    #pragma unroll
    for (int d = 0; d < 28; ++d)
        abv[d] = *(const bf16x8*)(ab + ((size_t)(d * 256 + tid)) * 8);

    // ---- SH basis (overlaps abv flight) ----
    const float ss = rdx*rdx + rdy*rdy + rdz*rdz;
    const float rn = rsqrtf(ss);
    const float x = rdx*rn, y = rdy*rn, z = rdz*rn;
    float sh[9];
    sh[0] = 0.28209479177387814f;
    sh[1] = -0.4886025119029199f * y;
    sh[2] =  0.4886025119029199f * z;
    sh[3] = -0.4886025119029199f * x;
    sh[4] =  1.0925484305920792f * x * y;
    sh[5] = -1.0925484305920792f * y * z;
    sh[6] =  0.31539156525252005f * (2.0f*z*z - x*x - y*y);
    sh[7] = -1.0925484305920792f * x * z;
    sh[8] =  0.5462742152960396f * (x*x - y*y);

    // ---- phase B: contract abv -> Bs[col = kp*8+c][a = tid] ----
    {
        const int a = tid;
        float accB[3][8];
        #pragma unroll
        for (int k = 0; k < 3; ++k)
            #pragma unroll
            for (int c = 0; c < 8; ++c) accB[k][c] = 0.0f;
        #pragma unroll
        for (int d = 0; d < 27; ++d) {
            const int kp = d / 9, j = d - kp * 9;
            const float s = sh[j];
            const unsigned int* u = (const unsigned int*)&abv[d];
            #pragma unroll
            for (int i = 0; i < 4; ++i) {
                const float flo = __uint_as_float(u[i] << 16);
                const float fhi = __uint_as_float(u[i] & 0xffff0000u);
                accB[kp][2*i]   = fmaf(s, flo, accB[kp][2*i]);
                accB[kp][2*i+1] = fmaf(s, fhi, accB[kp][2*i+1]);
            }
        }
        #pragma unroll
        for (int kp = 0; kp < 3; ++kp)
            #pragma unroll
            for (int c = 0; c < 8; ++c) {
                const int col = kp*8 + c;
                unsigned byte = ((unsigned)col << 9) + ((unsigned)a << 1);
                byte ^= (unsigned)((col & 7) << 4);
                *(unsigned short*)(bs + byte) = f32_to_bf16(accB[kp][c]);
            }
        // sigma row (d=27): already bf16 — store raw
        const unsigned short* sv = (const unsigned short*)&abv[27];
        #pragma unroll
        for (int c = 0; c < 8; ++c) {
            const int col = 24 + c;
            unsigned byte = ((unsigned)col << 9) + ((unsigned)a << 1);
            byte ^= (unsigned)((col & 7) << 4);
            *(unsigned short*)(bs + byte) = sv[c];
        }
    }

    // ---- phase A: trilinear weights ----
    if (tid < VALID) {
        const float fx = px - floorf(px);
        const float fy = py - floorf(py);
        const float fz = pz - floorf(pz);
        #pragma unroll
        for (int c = 0; c < 8; ++c) {
            const float wx = (c & 4) ? fx : 1.0f - fx;
            const float wy = (c & 2) ? fy : 1.0f - fy;
            const float wz = (c & 1) ? fz : 1.0f - fz;
            w_lds[tid][c] = wx * wy * wz;
        }
    }

    // ---- register prefetch pipeline for A-fragments, depth 3 ----
    // Lane l covers rows (l&15) and (l&15)+16 of the wave's 32-row tile,
    // k = (l>>4)*8 + 0..7 per step: 2 x 16B per row -> 4 dwordx4 per step.
    const int row  = lane & 15;
    const int kgrp = lane >> 4;
    const float* ga0 = q + (size_t)(ray*VALID + wav*32 + row) * NATOMS + kgrp*8;
    const float* ga1 = ga0 + 16 * NATOMS;

    f32x4 pf[3][4];

#define ISSUE_STEP(s, kk) do {                                                   \
    const float* _p0 = ga0 + (kk)*32;                                            \
    const float* _p1 = ga1 + (kk)*32;                                            \
    asm volatile("global_load_dwordx4 %0, %1, off" : "=v"(pf[s][0]) : "v"(_p0)   : "memory"); \
    asm volatile("global_load_dwordx4 %0, %1, off" : "=v"(pf[s][1]) : "v"(_p0+4) : "memory"); \
    asm volatile("global_load_dwordx4 %0, %1, off" : "=v"(pf[s][2]) : "v"(_p1)   : "memory"); \
    asm volatile("global_load_dwordx4 %0, %1, off" : "=v"(pf[s][3]) : "v"(_p1+4) : "memory"); \
} while (0)

    // All compiler VMEM (raysd/ipts/abv) fully consumed above -> vmcnt==0.
    asm volatile("s_waitcnt vmcnt(0)" ::: "memory");
    ISSUE_STEP(0, 0);
    ISSUE_STEP(1, 1);
    ISSUE_STEP(2, 2);

    // bs/w_lds visibility across waves: lgkmcnt drain + raw barrier
    // (avoids __syncthreads' vmcnt(0) drain of the prefetch queue).
    asm volatile("s_waitcnt lgkmcnt(0)" ::: "memory");
    __builtin_amdgcn_s_barrier();

    // ---- K-loop: 8 steps of K=32, register-prefetched, barrier-free ----
    f32x4 acc[2][2];
    #pragma unroll
    for (int m = 0; m < 2; ++m)
        #pragma unroll
        for (int n = 0; n < 2; ++n)
            acc[m][n] = (f32x4){0.f, 0.f, 0.f, 0.f};

    #pragma unroll
    for (int ks = 0; ks < 8; ++ks) {
        // wait for step ks's 4 loads; leave younger steps in flight
        if (ks <= 5)      asm volatile("s_waitcnt vmcnt(8)" ::: "memory");
        else if (ks == 6) asm volatile("s_waitcnt vmcnt(4)" ::: "memory");
        else              asm volatile("s_waitcnt vmcnt(0)" ::: "memory");
        __builtin_amdgcn_sched_barrier(0);   // rule #18: pin consumers below

        const int s = ks % 3;
        bf16x8 af0, af1;
        #pragma unroll
        for (int j = 0; j < 4; ++j) {
            af0[j]   = (short)f32_to_bf16(pf[s][0][j]);
            af0[j+4] = (short)f32_to_bf16(pf[s][1][j]);
            af1[j]   = (short)f32_to_bf16(pf[s][2][j]);
            af1[j+4] = (short)f32_to_bf16(pf[s][3][j]);
        }

        // reissue this slot for step ks+3 (after consumption)
        if (ks + 3 < 8) ISSUE_STEP(s, ks + 3);

        bf16x8 bfrag[2];
        const int abase = ks*32 + kgrp*8;
        #pragma unroll
        for (int nt = 0; nt < 2; ++nt) {
            const int col = nt*16 + row;
            unsigned byte = ((unsigned)col << 9) + ((unsigned)abase << 1);
            byte ^= (unsigned)((col & 7) << 4);
            bfrag[nt] = *(const bf16x8*)(bs + byte);
        }

        acc[0][0] = __builtin_amdgcn_mfma_f32_16x16x32_bf16(af0, bfrag[0], acc[0][0], 0, 0, 0);
        acc[0][1] = __builtin_amdgcn_mfma_f32_16x16x32_bf16(af0, bfrag[1], acc[0][1], 0, 0, 0);
        acc[1][0] = __builtin_amdgcn_mfma_f32_16x16x32_bf16(af1, bfrag[0], acc[1][0], 0, 0, 0);
        acc[1][1] = __builtin_amdgcn_mfma_f32_16x16x32_bf16(af1, bfrag[1], acc[1][1], 0, 0, 0);
    }
#undef ISSUE_STEP

    // ---- Epilogue: out[pt,kp] = sum_c w[pt,c] * C[pt, kp*8+c] ----
    // D layout: lane holds D[(lane>>4)*4 + r][lane&15]; col = kph*8 + cc.
    const int cc  = lane & 7;
    const int kph = (lane & 15) >> 3;
    #pragma unroll
    for (int m = 0; m < 2; ++m) {
        const int ptb = wav*32 + m*16 + kgrp*4;
        #pragma unroll
        for (int nt = 0; nt < 2; ++nt) {
            const int kp = nt*2 + kph;
            #pragma unroll
            for (int r = 0; r < 4; ++r) {
                float t = acc[m][nt][r] * w_lds[ptb + r][cc];
                t += __shfl_xor(t, 1);
                t += __shfl_xor(t, 2);
                t += __shfl_xor(t, 4);
                if (cc == 0) pr_lds[ptb + r][kp] = t;
            }
        }
    }
    __syncthreads();

    // ---- Render scan (wave 0): 2 samples per lane ----
    if (wav == 0) {
        const float rnorm = sqrtf(ss);
        const int i0 = lane * 2;
        const float t0 = intr[ray*257 + i0];
        const float t1 = intr[ray*257 + i0 + 1];
        const float t2 = intr[ray*257 + i0 + 2];
        const float d0 = (t1 - t0) * rnorm;
        const float d1 = (t2 - t1) * rnorm;
        const float s0 = fmaxf(pr_lds[i0][3],     0.0f);
        const float s1 = fmaxf(pr_lds[i0 + 1][3], 0.0f);
        const float a0 = 1.0f - __expf(-s0 * d0);
        const float a1 = 1.0f - __expf(-s1 * d1);
        const float f0 = 1.0f - a0 + 1e-10f;
        const float f1 = 1.0f - a1 + 1e-10f;

        float pprod = f0 * f1;
        #pragma unroll
        for (int off = 1; off < 64; off <<= 1) {
            float v = __shfl_up(pprod, off);
            if (lane >= off) pprod *= v;
        }
        float excl = __shfl_up(pprod, 1);
        if (lane == 0) excl = 1.0f;

        const float tr0 = excl;
        const float tr1 = excl * f0;
        const float al0 = a0 * tr0;
        const float al1 = a1 * tr1;
        const float mid0 = 0.5f * (t0 + t1);
        const float mid1 = 0.5f * (t1 + t2);

        const float r0 = 1.0f / (1.0f + __expf(-pr_lds[i0][0]));
        const float g0 = 1.0f / (1.0f + __expf(-pr_lds[i0][1]));
        const float b0 = 1.0f / (1.0f + __expf(-pr_lds[i0][2]));
        const float r1 = 1.0f / (1.0f + __expf(-pr_lds[i0 + 1][0]));
        const float g1 = 1.0f / (1.0f + __expf(-pr_lds[i0 + 1][1]));
        const float b1 = 1.0f / (1.0f + __expf(-pr_lds[i0 + 1][2]));

        float sum_r = al0*r0 + al1*r1;
        float sum_g = al0*g0 + al1*g1;
        float sum_b = al0*b0 + al1*b1;
        float sum_d = al0*mid0 + al1*mid1;
        float sum_a = al0 + al1;
        #pragma unroll
        for (int off = 1; off < 64; off <<= 1) {
            sum_r += __shfl_xor(sum_r, off);
            sum_g += __shfl_xor(sum_g, off);
            sum_b += __shfl_xor(sum_b, off);
            sum_d += __shfl_xor(sum_d, off);
            sum_a += __shfl_xor(sum_a, off);
        }
        if (lane == 0) {
            const float bkgd = 1.0f - sum_a;
            out_rgb[ray*3 + 0] = sum_r + bkgd;
            out_rgb[ray*3 + 1] = sum_g + bkgd;
            out_rgb[ray*3 + 2] = sum_b + bkgd;
            out_depth[ray]     = sum_d;
        }
        float2 av; av.x = a0; av.y = a1;
        *(float2*)(out_alpha + (size_t)ray*NINTRS + i0) = av;
        float2 zz; zz.x = 0.0f; zz.y = 0.0f;
        *(float2*)(out_alpha + (size_t)ray*NINTRS + VALID + i0) = zz;
    }
}

extern "C" void kernel_launch(void* const* d_in, const int* in_sizes, int n_in,
                              void* d_out, int out_size, void* d_ws, size_t ws_size,
                              hipStream_t stream)
{
    const float* q     = (const float*)d_in[0];
    const float* atoms = (const float*)d_in[1];
    const float* ipts  = (const float*)d_in[2];
    const float* intr  = (const float*)d_in[3];
    const float* raysd = (const float*)d_in[4];
    // d_in[5] (flat_idx) is b*NINTRS+i by construction; derived analytically.

    float* out = (float*)d_out;
    float* out_rgb   = out;
    float* out_alpha = out + BATCH*3;
    float* out_depth = out + BATCH*3 + (size_t)BATCH*NINTRS;

    unsigned short* ab = (unsigned short*)d_ws;   // 114688 B needed

    build_atomsB<<<28, 256, 0, stream>>>(atoms, ab);
    shdict_fused<<<BATCH, 256, 0, stream>>>(q, ab, ipts, intr, raysd,
                                            out_rgb, out_alpha, out_depth);
}

// Round 8
// 57.905 us; speedup vs baseline: 1.9180x; 1.0156x over previous
//
#include <hip/hip_runtime.h>
#include <hip/hip_bf16.h>
#include <math.h>

#define BATCH   2048
#define NINTRS  256
#define VALID   128
#define NATOMS  256
#define DDIM    28   // 3*9+1

typedef float  f32x4  __attribute__((ext_vector_type(4)));
typedef short  bf16x8 __attribute__((ext_vector_type(8)));

__device__ __forceinline__ unsigned short f32_to_bf16(float f) {
    unsigned int u = __float_as_uint(f);
    u = (u + 0x7FFFu + ((u >> 16) & 1u)) >> 16;   // RNE
    return (unsigned short)u;
}

// ---------------------------------------------------------------------------
// Pre-pass: ab[d][a] = 16B chunk {bf16 atoms[a][d][c], c=0..7}. [28][256] chunks
// = 112 KB, L2-resident. Main kernel's phase B reads it with lane-stride-16B
// fully-coalesced loads.
// ---------------------------------------------------------------------------
__global__ __launch_bounds__(256)
void build_atomsB(const float* __restrict__ atoms, unsigned short* __restrict__ ab)
{
    const int t = blockIdx.x * 256 + threadIdx.x;   // 0..7167
    const int d = t >> 8;          // 0..27
    const int a = t & 255;
    const float* src = atoms + ((size_t)a * DDIM + d) * 8;
    f32x4 v0 = *(const f32x4*)(src);
    f32x4 v1 = *(const f32x4*)(src + 4);
    bf16x8 o;
    #pragma unroll
    for (int j = 0; j < 4; ++j) {
        o[j]   = (short)f32_to_bf16(v0[j]);
        o[j+4] = (short)f32_to_bf16(v1[j]);
    }
    *(bf16x8*)(ab + (size_t)t * 8) = o;
}

// ---------------------------------------------------------------------------
// Main: one block per ray.
//   phase B: SH-contract ab -> Bs[32 col][256 a] bf16 in LDS. ab is read in
//            TWO 14-chunk halves reusing h[14] (56 VGPR vs 112) so the
//            phase-B register peak fits 4 blocks/CU.
//   K-loop:  C[pt,col] = sum_a q[pt,a]*Bs[col,a] via MFMA. A-operands
//            prefetched straight from global q into registers via inline-asm
//            global_load_dwordx4 (un-sinkable), DEPTH-4, counted vmcnt +
//            sched_barrier(0) (rule #18). No q LDS staging (LDS = 23 KB).
//   epilogue: trilinear-weight c-reduction + transmittance scan (wave 0).
// ---------------------------------------------------------------------------
__global__ __launch_bounds__(256, 4)
void shdict_fused(const float* __restrict__ q,      // [BATCH*VALID][256]
                  const unsigned short* __restrict__ ab,  // [28][256] bf16x8
                  const float* __restrict__ ipts,   // [BATCH*VALID][3]
                  const float* __restrict__ intr,   // [BATCH][257]
                  const float* __restrict__ raysd,  // [BATCH][3]
                  float* __restrict__ out_rgb,      // [BATCH][3]
                  float* __restrict__ out_alpha,    // [BATCH][256]
                  float* __restrict__ out_depth)    // [BATCH]
{
    __shared__ char  bs[32 * 256 * 2];      // 16 KB Bs[col][a] bf16, XOR-swizzled
    __shared__ float w_lds[VALID][9];       // trilinear weights (+1 pad)
    __shared__ float pr_lds[VALID][5];      // rgb0,rgb1,rgb2,sigma (+1 pad)

    const int ray  = blockIdx.x;
    const int tid  = threadIdx.x;
    const int lane = tid & 63;
    const int wav  = tid >> 6;

    // ---- scalar input loads; consumed immediately below ----
    const float rdx = raysd[ray*3+0], rdy = raysd[ray*3+1], rdz = raysd[ray*3+2];
    float px = 0.f, py = 0.f, pz = 0.f;
    if (tid < VALID) {
        const int n = ray * VALID + tid;
        px = ipts[n*3+0]*128.0f + 1e-5f;
        py = ipts[n*3+1]*128.0f + 1e-5f;
        pz = ipts[n*3+2]*128.0f + 1e-5f;
    }

    // ---- SH basis ----
    const float ss = rdx*rdx + rdy*rdy + rdz*rdz;
    const float rn = rsqrtf(ss);
    const float x = rdx*rn, y = rdy*rn, z = rdz*rn;
    float sh[9];
    sh[0] = 0.28209479177387814f;
    sh[1] = -0.4886025119029199f * y;
    sh[2] =  0.4886025119029199f * z;
    sh[3] = -0.4886025119029199f * x;
    sh[4] =  1.0925484305920792f * x * y;
    sh[5] = -1.0925484305920792f * y * z;
    sh[6] =  0.31539156525252005f * (2.0f*z*z - x*x - y*y);
    sh[7] = -1.0925484305920792f * x * z;
    sh[8] =  0.5462742152960396f * (x-y)*(x+y);

    // ---- phase A: trilinear weights (consumes px/py/pz early) ----
    if (tid < VALID) {
        const float fx = px - floorf(px);
        const float fy = py - floorf(py);
        const float fz = pz - floorf(pz);
        #pragma unroll
        for (int c = 0; c < 8; ++c) {
            const float wx = (c & 4) ? fx : 1.0f - fx;
            const float wy = (c & 2) ? fy : 1.0f - fy;
            const float wz = (c & 1) ? fz : 1.0f - fz;
            w_lds[tid][c] = wx * wy * wz;
        }
    }

    // ---- phase B: contract ab -> Bs[col = kp*8+c][a = tid], two halves ----
    {
        const int a = tid;
        float accB[3][8];
        #pragma unroll
        for (int k = 0; k < 3; ++k)
            #pragma unroll
            for (int c = 0; c < 8; ++c) accB[k][c] = 0.0f;

        bf16x8 h[14];
        // half 1: d = 0..13
        #pragma unroll
        for (int d = 0; d < 14; ++d)
            h[d] = *(const bf16x8*)(ab + ((size_t)(d * 256 + a)) * 8);
        #pragma unroll
        for (int d = 0; d < 14; ++d) {
            const int kp = d / 9, j = d - kp * 9;
            const float s = sh[j];
            const unsigned int* u = (const unsigned int*)&h[d];
            #pragma unroll
            for (int i = 0; i < 4; ++i) {
                const float flo = __uint_as_float(u[i] << 16);
                const float fhi = __uint_as_float(u[i] & 0xffff0000u);
                accB[kp][2*i]   = fmaf(s, flo, accB[kp][2*i]);
                accB[kp][2*i+1] = fmaf(s, fhi, accB[kp][2*i+1]);
            }
        }
        __builtin_amdgcn_sched_barrier(0);   // don't hoist half-2 loads above
        // half 2: d = 14..27 (d=27 is sigma, kept raw in h[13])
        #pragma unroll
        for (int d = 0; d < 14; ++d)
            h[d] = *(const bf16x8*)(ab + ((size_t)((d + 14) * 256 + a)) * 8);
        #pragma unroll
        for (int d = 0; d < 13; ++d) {
            const int dd = d + 14;
            const int kp = dd / 9, j = dd - kp * 9;
            const float s = sh[j];
            const unsigned int* u = (const unsigned int*)&h[d];
            #pragma unroll
            for (int i = 0; i < 4; ++i) {
                const float flo = __uint_as_float(u[i] << 16);
                const float fhi = __uint_as_float(u[i] & 0xffff0000u);
                accB[kp][2*i]   = fmaf(s, flo, accB[kp][2*i]);
                accB[kp][2*i+1] = fmaf(s, fhi, accB[kp][2*i+1]);
            }
        }
        #pragma unroll
        for (int kp = 0; kp < 3; ++kp)
            #pragma unroll
            for (int c = 0; c < 8; ++c) {
                const int col = kp*8 + c;
                unsigned byte = ((unsigned)col << 9) + ((unsigned)a << 1);
                byte ^= (unsigned)((col & 7) << 4);
                *(unsigned short*)(bs + byte) = f32_to_bf16(accB[kp][c]);
            }
        const unsigned short* sv = (const unsigned short*)&h[13];
        #pragma unroll
        for (int c = 0; c < 8; ++c) {
            const int col = 24 + c;
            unsigned byte = ((unsigned)col << 9) + ((unsigned)a << 1);
            byte ^= (unsigned)((col & 7) << 4);
            *(unsigned short*)(bs + byte) = sv[c];
        }
    }

    // ---- register prefetch pipeline for A-fragments, depth 4 ----
    // Lane l covers rows (l&15) and (l&15)+16, k = (l>>4)*8 + 0..7 per step.
    const int row  = lane & 15;
    const int kgrp = lane >> 4;
    const float* ga0 = q + (size_t)(ray*VALID + wav*32 + row) * NATOMS + kgrp*8;
    const float* ga1 = ga0 + 16 * NATOMS;

    f32x4 pf[4][4];

#define ISSUE_STEP(s, kk) do {                                                   \
    const float* _p0 = ga0 + (kk)*32;                                            \
    const float* _p1 = ga1 + (kk)*32;                                            \
    asm volatile("global_load_dwordx4 %0, %1, off" : "=v"(pf[s][0]) : "v"(_p0)   : "memory"); \
    asm volatile("global_load_dwordx4 %0, %1, off" : "=v"(pf[s][1]) : "v"(_p0+4) : "memory"); \
    asm volatile("global_load_dwordx4 %0, %1, off" : "=v"(pf[s][2]) : "v"(_p1)   : "memory"); \
    asm volatile("global_load_dwordx4 %0, %1, off" : "=v"(pf[s][3]) : "v"(_p1+4) : "memory"); \
} while (0)

    // All compiler VMEM (raysd/ipts/ab halves) fully consumed above -> vmcnt==0.
    asm volatile("s_waitcnt vmcnt(0)" ::: "memory");
    ISSUE_STEP(0, 0);
    ISSUE_STEP(1, 1);
    ISSUE_STEP(2, 2);
    ISSUE_STEP(3, 3);

    // bs/w_lds visibility: lgkmcnt drain + raw barrier (no vmcnt drain).
    asm volatile("s_waitcnt lgkmcnt(0)" ::: "memory");
    __builtin_amdgcn_s_barrier();

    // ---- K-loop: 8 steps of K=32, depth-4 register pipeline ----
    f32x4 acc[2][2];
    #pragma unroll
    for (int m = 0; m < 2; ++m)
        #pragma unroll
        for (int n = 0; n < 2; ++n)
            acc[m][n] = (f32x4){0.f, 0.f, 0.f, 0.f};

    #pragma unroll
    for (int ks = 0; ks < 8; ++ks) {
        // wait for step ks's 4 loads; leave younger in flight
        if (ks <= 4)      asm volatile("s_waitcnt vmcnt(12)" ::: "memory");
        else if (ks == 5) asm volatile("s_waitcnt vmcnt(8)"  ::: "memory");
        else if (ks == 6) asm volatile("s_waitcnt vmcnt(4)"  ::: "memory");
        else              asm volatile("s_waitcnt vmcnt(0)"  ::: "memory");
        __builtin_amdgcn_sched_barrier(0);   // rule #18: pin consumers below

        const int s = ks & 3;
        bf16x8 af0, af1;
        #pragma unroll
        for (int j = 0; j < 4; ++j) {
            af0[j]   = (short)f32_to_bf16(pf[s][0][j]);
            af0[j+4] = (short)f32_to_bf16(pf[s][1][j]);
            af1[j]   = (short)f32_to_bf16(pf[s][2][j]);
            af1[j+4] = (short)f32_to_bf16(pf[s][3][j]);
        }

        // reissue this slot for step ks+4 (after consumption)
        if (ks + 4 < 8) ISSUE_STEP(s, ks + 4);

        bf16x8 bfrag[2];
        const int abase = ks*32 + kgrp*8;
        #pragma unroll
        for (int nt = 0; nt < 2; ++nt) {
            const int col = nt*16 + row;
            unsigned byte = ((unsigned)col << 9) + ((unsigned)abase << 1);
            byte ^= (unsigned)((col & 7) << 4);
            bfrag[nt] = *(const bf16x8*)(bs + byte);
        }

        acc[0][0] = __builtin_amdgcn_mfma_f32_16x16x32_bf16(af0, bfrag[0], acc[0][0], 0, 0, 0);
        acc[0][1] = __builtin_amdgcn_mfma_f32_16x16x32_bf16(af0, bfrag[1], acc[0][1], 0, 0, 0);
        acc[1][0] = __builtin_amdgcn_mfma_f32_16x16x32_bf16(af1, bfrag[0], acc[1][0], 0, 0, 0);
        acc[1][1] = __builtin_amdgcn_mfma_f32_16x16x32_bf16(af1, bfrag[1], acc[1][1], 0, 0, 0);
    }
#undef ISSUE_STEP

    // ---- Epilogue: out[pt,kp] = sum_c w[pt,c] * C[pt, kp*8+c] ----
    // D layout: lane holds D[(lane>>4)*4 + r][lane&15]; col = kph*8 + cc.
    const int cc  = lane & 7;
    const int kph = (lane & 15) >> 3;
    #pragma unroll
    for (int m = 0; m < 2; ++m) {
        const int ptb = wav*32 + m*16 + kgrp*4;
        #pragma unroll
        for (int nt = 0; nt < 2; ++nt) {
            const int kp = nt*2 + kph;
            #pragma unroll
            for (int r = 0; r < 4; ++r) {
                float t = acc[m][nt][r] * w_lds[ptb + r][cc];
                t += __shfl_xor(t, 1);
                t += __shfl_xor(t, 2);
                t += __shfl_xor(t, 4);
                if (cc == 0) pr_lds[ptb + r][kp] = t;
            }
        }
    }
    __syncthreads();

    // ---- Render scan (wave 0): 2 samples per lane ----
    if (wav == 0) {
        const float rnorm = sqrtf(ss);
        const int i0 = lane * 2;
        const float t0 = intr[ray*257 + i0];
        const float t1 = intr[ray*257 + i0 + 1];
        const float t2 = intr[ray*257 + i0 + 2];
        const float d0 = (t1 - t0) * rnorm;
        const float d1 = (t2 - t1) * rnorm;
        const float s0 = fmaxf(pr_lds[i0][3],     0.0f);
        const float s1 = fmaxf(pr_lds[i0 + 1][3], 0.0f);
        const float a0 = 1.0f - __expf(-s0 * d0);
        const float a1 = 1.0f - __expf(-s1 * d1);
        const float f0 = 1.0f - a0 + 1e-10f;
        const float f1 = 1.0f - a1 + 1e-10f;

        float pprod = f0 * f1;
        #pragma unroll
        for (int off = 1; off < 64; off <<= 1) {
            float v = __shfl_up(pprod, off);
            if (lane >= off) pprod *= v;
        }
        float excl = __shfl_up(pprod, 1);
        if (lane == 0) excl = 1.0f;

        const float tr0 = excl;
        const float tr1 = excl * f0;
        const float al0 = a0 * tr0;
        const float al1 = a1 * tr1;
        const float mid0 = 0.5f * (t0 + t1);
        const float mid1 = 0.5f * (t1 + t2);

        const float r0 = 1.0f / (1.0f + __expf(-pr_lds[i0][0]));
        const float g0 = 1.0f / (1.0f + __expf(-pr_lds[i0][1]));
        const float b0 = 1.0f / (1.0f + __expf(-pr_lds[i0][2]));
        const float r1 = 1.0f / (1.0f + __expf(-pr_lds[i0 + 1][0]));
        const float g1 = 1.0f / (1.0f + __expf(-pr_lds[i0 + 1][1]));
        const float b1 = 1.0f / (1.0f + __expf(-pr_lds[i0 + 1][2]));

        float sum_r = al0*r0 + al1*r1;
        float sum_g = al0*g0 + al1*g1;
        float sum_b = al0*b0 + al1*b1;
        float sum_d = al0*mid0 + al1*mid1;
        float sum_a = al0 + al1;
        #pragma unroll
        for (int off = 1; off < 64; off <<= 1) {
            sum_r += __shfl_xor(sum_r, off);
            sum_g += __shfl_xor(sum_g, off);
            sum_b += __shfl_xor(sum_b, off);
            sum_d += __shfl_xor(sum_d, off);
            sum_a += __shfl_xor(sum_a, off);
        }
        if (lane == 0) {
            const float bkgd = 1.0f - sum_a;
            out_rgb[ray*3 + 0] = sum_r + bkgd;
            out_rgb[ray*3 + 1] = sum_g + bkgd;
            out_rgb[ray*3 + 2] = sum_b + bkgd;
            out_depth[ray]     = sum_d;
        }
        float2 av; av.x = a0; av.y = a1;
        *(float2*)(out_alpha + (size_t)ray*NINTRS + i0) = av;
        float2 zz; zz.x = 0.0f; zz.y = 0.0f;
        *(float2*)(out_alpha + (size_t)ray*NINTRS + VALID + i0) = zz;
    }
}

extern "C" void kernel_launch(void* const* d_in, const int* in_sizes, int n_in,
                              void* d_out, int out_size, void* d_ws, size_t ws_size,
                              hipStream_t stream)
{
    const float* q     = (const float*)d_in[0];
    const float* atoms = (const float*)d_in[1];
    const float* ipts  = (const float*)d_in[2];
    const float* intr  = (const float*)d_in[3];
    const float* raysd = (const float*)d_in[4];
    // d_in[5] (flat_idx) is b*NINTRS+i by construction; derived analytically.

    float* out = (float*)d_out;
    float* out_rgb   = out;
    float* out_alpha = out + BATCH*3;
    float* out_depth = out + BATCH*3 + (size_t)BATCH*NINTRS;

    unsigned short* ab = (unsigned short*)d_ws;   // 114688 B needed

    build_atomsB<<<28, 256, 0, stream>>>(atoms, ab);
    shdict_fused<<<BATCH, 256, 0, stream>>>(q, ab, ipts, intr, raysd,
                                            out_rgb, out_alpha, out_depth);
}